// Round 4
// baseline (2826.574 us; speedup 1.0000x reference)
//
#include <hip/hip_runtime.h>
#include <stdint.h>

// ---- problem constants ----
#define Bz 8
#define Tz 1024
#define Cz 768
#define Hz 8
#define Dz 96
#define BHz 64            // Bz*Hz
#define Kz 768
#define VS 138            // Vsm stride: VS/2 odd -> PV b64 reads spread all 32 banks

typedef __bf16 bf16x8 __attribute__((ext_vector_type(8)));
typedef unsigned short u16x8 __attribute__((ext_vector_type(8)));
typedef float f32x4 __attribute__((ext_vector_type(4)));
typedef short s16x4 __attribute__((ext_vector_type(4)));

__device__ __forceinline__ unsigned short f2bf(float f) {
  union { float f; unsigned int u; } v; v.f = f;
  unsigned int u = v.u;
  return (unsigned short)((u + 0x7fffu + ((u >> 16) & 1u)) >> 16);
}

__device__ __forceinline__ s16x4 pack4(f32x4 p) {
  s16x4 o;
  o[0] = (short)f2bf(p[0]); o[1] = (short)f2bf(p[1]);
  o[2] = (short)f2bf(p[2]); o[3] = (short)f2bf(p[3]);
  return o;
}

// async global->LDS, 16B per lane; LDS dest is wave-uniform base (+lane*16 implicit)
typedef const __attribute__((address_space(1))) void* gas_ptr;
typedef __attribute__((address_space(3))) void* las_ptr;
__device__ __forceinline__ void gl16(const void* g, void* l) {
  __builtin_amdgcn_global_load_lds((gas_ptr)g, (las_ptr)l, 16, 0, 0);
}

// ---- cast x (fp32) -> bf16, 4 elems/thread ----
__global__ __launch_bounds__(256) void cast_f32_bf16(const float* __restrict__ in,
                                                     unsigned short* __restrict__ out) {
  int i = (blockIdx.x * 256 + threadIdx.x) * 4;
  float4 v = *(const float4*)(in + i);
  union { unsigned short s[4]; uint2 u; } o;
  o.s[0] = f2bf(v.x); o.s[1] = f2bf(v.y); o.s[2] = f2bf(v.z); o.s[3] = f2bf(v.w);
  *(uint2*)(out + i) = o.u;
}

// ---- transpose + cast: in[R][Cc] fp32 -> out[Cc][R] bf16 ----
__global__ __launch_bounds__(256) void transpose_cast(const float* __restrict__ in,
                                                      unsigned short* __restrict__ out,
                                                      int R, int Cc) {
  __shared__ unsigned short t[64][72];
  int bx = blockIdx.x * 64;   // col base of in
  int by = blockIdx.y * 64;   // row base of in
  int tid = threadIdx.x;
#pragma unroll
  for (int i = 0; i < 16; i++) {
    int idx = tid + i * 256;
    int r = idx >> 6, c = idx & 63;
    t[c][r] = f2bf(in[(by + r) * Cc + bx + c]);
  }
  __syncthreads();
#pragma unroll
  for (int i = 0; i < 16; i++) {
    int idx = tid + i * 256;
    int r = idx >> 6, c = idx & 63;
    out[(bx + r) * R + by + c] = t[r][c];
  }
}

// ---- 128x128 MFMA bf16 GEMM with global_load_lds staging (m97 structure) ----
template <int MODE>
__global__ __launch_bounds__(256)
void gemm128(const unsigned short* __restrict__ A,
             const unsigned short* __restrict__ Bt,
             unsigned short* __restrict__ obf,
             float* __restrict__ of32) {
  __shared__ unsigned short Asm[128 * 32];  // unpadded: required by global_load_lds lane order
  __shared__ unsigned short Bsm[128 * 32];
  const int tid = threadIdx.x;
  const int wave = tid >> 6, lane = tid & 63;
  const int quad = lane >> 4, l16 = lane & 15;
  const int bm = blockIdx.x, bn = blockIdx.y;
  const int wm = (wave >> 1) * 64, wn = (wave & 1) * 64;

  f32x4 zero = {0.f, 0.f, 0.f, 0.f};
  f32x4 acc[4][4];
#pragma unroll
  for (int i = 0; i < 4; i++)
#pragma unroll
    for (int j = 0; j < 4; j++) acc[i][j] = zero;

  const int rr = lane >> 2, c8 = (lane & 3) * 8;
  const unsigned short* Ag0 = A + (size_t)(bm * 128 + wave * 32 + rr) * Kz + c8;
  const unsigned short* Ag1 = Ag0 + 16 * Kz;
  const unsigned short* Bg0 = Bt + (size_t)(bn * 128 + wave * 32 + rr) * Kz + c8;
  const unsigned short* Bg1 = Bg0 + 16 * Kz;
  unsigned short* lA0 = &Asm[wave * 1024];
  unsigned short* lA1 = lA0 + 512;
  unsigned short* lB0 = &Bsm[wave * 1024];
  unsigned short* lB1 = lB0 + 512;

  for (int k0 = 0; k0 < Kz; k0 += 32) {
    __syncthreads();
    gl16(Ag0 + k0, lA0);
    gl16(Ag1 + k0, lA1);
    gl16(Bg0 + k0, lB0);
    gl16(Bg1 + k0, lB1);
    __syncthreads();
    bf16x8 af[4], bfr[4];
#pragma unroll
    for (int mi = 0; mi < 4; mi++)
      af[mi] = *(const bf16x8*)&Asm[(wm + mi * 16 + l16) * 32 + quad * 8];
#pragma unroll
    for (int ni = 0; ni < 4; ni++)
      bfr[ni] = *(const bf16x8*)&Bsm[(wn + ni * 16 + l16) * 32 + quad * 8];
#pragma unroll
    for (int mi = 0; mi < 4; mi++)
#pragma unroll
      for (int ni = 0; ni < 4; ni++)
        acc[mi][ni] = __builtin_amdgcn_mfma_f32_16x16x32_bf16(af[mi], bfr[ni], acc[mi][ni], 0, 0, 0);
  }

#pragma unroll
  for (int mi = 0; mi < 4; mi++) {
    int row = bm * 128 + wm + mi * 16 + quad * 4;
    if (MODE == 0) {
      int b = row >> 10;
      int t = row & 1023;
#pragma unroll
      for (int ni = 0; ni < 4; ni++) {
        int col = bn * 128 + wn + ni * 16 + l16;
        int which = col / 768;
        int cc = col - which * 768;
        int h = cc / 96;
        int d = cc - h * 96;
        int base = ((which * 64 + b * 8 + h) * 1024 + t) * 96 + d;
#pragma unroll
        for (int r = 0; r < 4; r++) obf[base + r * 96] = f2bf(acc[mi][ni][r]);
      }
    } else {
#pragma unroll
      for (int ni = 0; ni < 4; ni++) {
        int col = bn * 128 + wn + ni * 16 + l16;
#pragma unroll
        for (int r = 0; r < 4; r++) of32[(row + r) * 768 + col] = acc[mi][ni][r];
      }
    }
  }
}

// ---- flash attention v4: S^T formulation, P in registers, m-tiles sequential ----
// 1 block = (b,h) x 128 q-rows; 4 waves x 32 rows (2 m-tiles processed one at a time)
// S^T = K Q^T ; O^T = V^T P^T via v_mfma_f32_16x16x16bf16_1k, P consumed per-ni (no array)
__global__ __launch_bounds__(256, 3)
void attn(const unsigned short* __restrict__ qkv, unsigned short* __restrict__ y) {
  const int bh = blockIdx.x;
  const int q0 = (7 - blockIdx.y) * 128;   // heavy blocks dispatch first
  const int tid = threadIdx.x;
  const int wave = tid >> 6, lane = tid & 63;
  const int quad = lane >> 4, l16 = lane & 15;
  const int qw0 = q0 + wave * 32;
  const int b = bh >> 3, h = bh & 7;

  const unsigned short* Qh = qkv + bh * Tz * Dz;
  const unsigned short* Kh = qkv + (BHz + bh) * Tz * Dz;
  const unsigned short* Vh = qkv + (2 * BHz + bh) * Tz * Dz;

  __shared__ unsigned short Vsm[96 * VS];   // V^T [d][s]

  // Q B-frags: n=l16 -> q row, k=quad*8+j -> d
  bf16x8 aq[2][3];
#pragma unroll
  for (int mi = 0; mi < 2; mi++)
#pragma unroll
    for (int kd = 0; kd < 3; kd++)
      aq[mi][kd] = *(const bf16x8*)(Qh + (qw0 + mi * 16 + l16) * Dz + kd * 32 + quad * 8);

  f32x4 zero = {0.f, 0.f, 0.f, 0.f};
  f32x4 acc_o[2][6];   // O^T: col=l16=q, row=quad*4+r=d (per 16-d tile)
#pragma unroll
  for (int mi = 0; mi < 2; mi++)
#pragma unroll
    for (int i = 0; i < 6; i++) acc_o[mi][i] = zero;
  const float NEG = -__builtin_inff();
  float mrow[2] = {NEG, NEG}, lrow[2] = {0.f, 0.f};   // per-lane: q = l16 (+16*mi)
  const float scale = 0.10206207261596577f;  // 1/sqrt(96)

  // conflict-free V^T staging map: lane = s index -> consecutive LDS addresses
  const int sg = tid & 127;
  const int g0 = tid >> 7;
  const unsigned short* Vrow = Vh + sg * Dz;

  for (int s0 = 0; s0 <= q0; s0 += 128) {
    __syncthreads();                 // WAR: prior iter's Vsm reads done
#pragma unroll
    for (int i = 0; i < 6; i++) {
      int g = g0 + 2 * i;
      u16x8 v = *(const u16x8*)(Vrow + s0 * Dz + g * 8);
#pragma unroll
      for (int jj = 0; jj < 8; jj++) Vsm[(g * 8 + jj) * VS + sg] = v[jj];
    }
    __syncthreads();                 // Vsm ready

#pragma unroll
    for (int mi = 0; mi < 2; mi++) {
      const int nl = min(7, (qw0 + mi * 16 + 15 - s0) >> 4);
      const int t_abs = qw0 + mi * 16 + l16;

      // ---- S^T = K Q^T : lane holds S^T[s=quad*4+r][q=l16] per 16-s tile
      f32x4 sacc[8];
#pragma unroll
      for (int ni = 0; ni < 8; ni++) {
        if (ni <= nl) {
          sacc[ni] = zero;
#pragma unroll
          for (int kd = 0; kd < 3; kd++) {
            bf16x8 ak = *(const bf16x8*)(Kh + (s0 + ni * 16 + l16) * Dz + kd * 32 + quad * 8);
            sacc[ni] = __builtin_amdgcn_mfma_f32_16x16x32_bf16(ak, aq[mi][kd], sacc[ni], 0, 0, 0);
          }
        }
      }

      // ---- mask + row max (per-lane scalar: q = l16)
      float rmax = NEG;
#pragma unroll
      for (int ni = 0; ni < 8; ni++) {
        if (ni <= nl) {
#pragma unroll
          for (int r = 0; r < 4; r++) {
            int s_abs = s0 + ni * 16 + quad * 4 + r;
            float v = (s_abs > t_abs) ? NEG : sacc[ni][r] * scale;
            sacc[ni][r] = v;
            rmax = fmaxf(rmax, v);
          }
        }
      }
      rmax = fmaxf(rmax, __shfl_xor(rmax, 16));
      rmax = fmaxf(rmax, __shfl_xor(rmax, 32));
      float mnew = fmaxf(mrow[mi], rmax);
      float alpha = __expf(mrow[mi] - mnew);
      mrow[mi] = mnew;
#pragma unroll
      for (int di = 0; di < 6; di++)
#pragma unroll
        for (int r = 0; r < 4; r++) acc_o[mi][di][r] *= alpha;

      // ---- exp + pack + immediate PV (P never stored; fused per s-tile)
      float rsum = 0.f;
#pragma unroll
      for (int ni = 0; ni < 8; ni++) {
        if (ni <= nl) {
          f32x4 p;
#pragma unroll
          for (int r = 0; r < 4; r++) {
            p[r] = __expf(sacc[ni][r] - mnew);   // masked -> exp(-inf)=0
            rsum += p[r];
          }
          s16x4 pk = pack4(p);
#pragma unroll
          for (int di = 0; di < 6; di++) {
            s16x4 av = *(const s16x4*)&Vsm[(di * 16 + l16) * VS + ni * 16 + quad * 4];
            acc_o[mi][di] = __builtin_amdgcn_mfma_f32_16x16x16bf16_1k(av, pk, acc_o[mi][di], 0, 0, 0);
          }
        }
      }
      rsum += __shfl_xor(rsum, 16);
      rsum += __shfl_xor(rsum, 32);
      lrow[mi] = lrow[mi] * alpha + rsum;
    }
  }

  // epilogue: lane holds O^T[d=di*16+quad*4+r][q=l16]; 8B stores, d-contiguous
#pragma unroll
  for (int mi = 0; mi < 2; mi++) {
    float linv = 1.f / lrow[mi];
    int t = qw0 + mi * 16 + l16;
#pragma unroll
    for (int di = 0; di < 6; di++) {
      union { unsigned short s[4]; uint2 u; } o;
#pragma unroll
      for (int r = 0; r < 4; r++) o.s[r] = f2bf(acc_o[mi][di][r] * linv);
      int d = di * 16 + quad * 4;
      *(uint2*)&y[(size_t)(b * Tz + t) * Cz + h * Dz + d] = o.u;
    }
  }
}

// ---- workspace layout (bytes) ----
#define OFF_XB   0u
#define OFF_WAT  12582912u            // 8192*768*2
#define OFF_WPT  16121856u            // + 2304*768*2
#define OFF_QKV  17301504u            // + 768*768*2
#define OFF_Y    55050240u            // + 3*64*1024*96*2

extern "C" void kernel_launch(void* const* d_in, const int* in_sizes, int n_in,
                              void* d_out, int out_size, void* d_ws, size_t ws_size,
                              hipStream_t stream) {
  const float* x  = (const float*)d_in[0];
  const float* Wa = (const float*)d_in[1];
  const float* Wp = (const float*)d_in[2];
  float* out = (float*)d_out;
  uint8_t* ws = (uint8_t*)d_ws;
  unsigned short* xb  = (unsigned short*)(ws + OFF_XB);
  unsigned short* Wat = (unsigned short*)(ws + OFF_WAT);
  unsigned short* Wpt = (unsigned short*)(ws + OFF_WPT);
  unsigned short* qkv = (unsigned short*)(ws + OFF_QKV);
  unsigned short* y   = (unsigned short*)(ws + OFF_Y);

  cast_f32_bf16<<<6144, 256, 0, stream>>>(x, xb);
  transpose_cast<<<dim3(36, 12), 256, 0, stream>>>(Wa, Wat, 768, 2304);
  transpose_cast<<<dim3(12, 12), 256, 0, stream>>>(Wp, Wpt, 768, 768);
  gemm128<0><<<dim3(64, 18), 256, 0, stream>>>(xb, Wat, qkv, nullptr);
  attn<<<dim3(64, 8), 256, 0, stream>>>(qkv, y);
  gemm128<1><<<dim3(64, 6), 256, 0, stream>>>(y, Wpt, nullptr, out);
}

// Round 5
// 917.320 us; speedup vs baseline: 3.0813x; 3.0813x over previous
//
#include <hip/hip_runtime.h>
#include <stdint.h>

// ---- problem constants ----
#define Bz 8
#define Tz 1024
#define Cz 768
#define Hz 8
#define Dz 96
#define BHz 64            // Bz*Hz
#define Kz 768
#define VS 136            // Vsm stride (elems): keeps b64 PV reads 8B-aligned, ~2 lanes/bank

typedef __bf16 bf16x8 __attribute__((ext_vector_type(8)));
typedef unsigned short u16x8 __attribute__((ext_vector_type(8)));
typedef float f32x4 __attribute__((ext_vector_type(4)));
typedef short s16x4 __attribute__((ext_vector_type(4)));

__device__ __forceinline__ unsigned short f2bf(float f) {
  union { float f; unsigned int u; } v; v.f = f;
  unsigned int u = v.u;
  return (unsigned short)((u + 0x7fffu + ((u >> 16) & 1u)) >> 16);
}

__device__ __forceinline__ s16x4 pack4(f32x4 p) {
  s16x4 o;
  o[0] = (short)f2bf(p[0]); o[1] = (short)f2bf(p[1]);
  o[2] = (short)f2bf(p[2]); o[3] = (short)f2bf(p[3]);
  return o;
}

// async global->LDS, 16B per lane; LDS dest is wave-uniform base (+lane*16 implicit)
typedef const __attribute__((address_space(1))) void* gas_ptr;
typedef __attribute__((address_space(3))) void* las_ptr;
__device__ __forceinline__ void gl16(const void* g, void* l) {
  __builtin_amdgcn_global_load_lds((gas_ptr)g, (las_ptr)l, 16, 0, 0);
}

// ---- cast x (fp32) -> bf16, 4 elems/thread ----
__global__ __launch_bounds__(256) void cast_f32_bf16(const float* __restrict__ in,
                                                     unsigned short* __restrict__ out) {
  int i = (blockIdx.x * 256 + threadIdx.x) * 4;
  float4 v = *(const float4*)(in + i);
  union { unsigned short s[4]; uint2 u; } o;
  o.s[0] = f2bf(v.x); o.s[1] = f2bf(v.y); o.s[2] = f2bf(v.z); o.s[3] = f2bf(v.w);
  *(uint2*)(out + i) = o.u;
}

// ---- transpose + cast: in[R][Cc] fp32 -> out[Cc][R] bf16 ----
__global__ __launch_bounds__(256) void transpose_cast(const float* __restrict__ in,
                                                      unsigned short* __restrict__ out,
                                                      int R, int Cc) {
  __shared__ unsigned short t[64][72];
  int bx = blockIdx.x * 64;   // col base of in
  int by = blockIdx.y * 64;   // row base of in
  int tid = threadIdx.x;
#pragma unroll
  for (int i = 0; i < 16; i++) {
    int idx = tid + i * 256;
    int r = idx >> 6, c = idx & 63;
    t[c][r] = f2bf(in[(by + r) * Cc + bx + c]);
  }
  __syncthreads();
#pragma unroll
  for (int i = 0; i < 16; i++) {
    int idx = tid + i * 256;
    int r = idx >> 6, c = idx & 63;
    out[(bx + r) * R + by + c] = t[r][c];
  }
}

// ---- 128x128 MFMA bf16 GEMM with global_load_lds staging (m97 structure) ----
template <int MODE>
__global__ __launch_bounds__(256)
void gemm128(const unsigned short* __restrict__ A,
             const unsigned short* __restrict__ Bt,
             unsigned short* __restrict__ obf,
             float* __restrict__ of32) {
  __shared__ unsigned short Asm[128 * 32];  // unpadded: required by global_load_lds lane order
  __shared__ unsigned short Bsm[128 * 32];
  const int tid = threadIdx.x;
  const int wave = tid >> 6, lane = tid & 63;
  const int quad = lane >> 4, l16 = lane & 15;
  const int bm = blockIdx.x, bn = blockIdx.y;
  const int wm = (wave >> 1) * 64, wn = (wave & 1) * 64;

  f32x4 zero = {0.f, 0.f, 0.f, 0.f};
  f32x4 acc[4][4];
#pragma unroll
  for (int i = 0; i < 4; i++)
#pragma unroll
    for (int j = 0; j < 4; j++) acc[i][j] = zero;

  const int rr = lane >> 2, c8 = (lane & 3) * 8;
  const unsigned short* Ag0 = A + (size_t)(bm * 128 + wave * 32 + rr) * Kz + c8;
  const unsigned short* Ag1 = Ag0 + 16 * Kz;
  const unsigned short* Bg0 = Bt + (size_t)(bn * 128 + wave * 32 + rr) * Kz + c8;
  const unsigned short* Bg1 = Bg0 + 16 * Kz;
  unsigned short* lA0 = &Asm[wave * 1024];
  unsigned short* lA1 = lA0 + 512;
  unsigned short* lB0 = &Bsm[wave * 1024];
  unsigned short* lB1 = lB0 + 512;

  for (int k0 = 0; k0 < Kz; k0 += 32) {
    __syncthreads();
    gl16(Ag0 + k0, lA0);
    gl16(Ag1 + k0, lA1);
    gl16(Bg0 + k0, lB0);
    gl16(Bg1 + k0, lB1);
    __syncthreads();
    bf16x8 af[4], bfr[4];
#pragma unroll
    for (int mi = 0; mi < 4; mi++)
      af[mi] = *(const bf16x8*)&Asm[(wm + mi * 16 + l16) * 32 + quad * 8];
#pragma unroll
    for (int ni = 0; ni < 4; ni++)
      bfr[ni] = *(const bf16x8*)&Bsm[(wn + ni * 16 + l16) * 32 + quad * 8];
#pragma unroll
    for (int mi = 0; mi < 4; mi++)
#pragma unroll
      for (int ni = 0; ni < 4; ni++)
        acc[mi][ni] = __builtin_amdgcn_mfma_f32_16x16x32_bf16(af[mi], bfr[ni], acc[mi][ni], 0, 0, 0);
  }

#pragma unroll
  for (int mi = 0; mi < 4; mi++) {
    int row = bm * 128 + wm + mi * 16 + quad * 4;
    if (MODE == 0) {
      int b = row >> 10;
      int t = row & 1023;
#pragma unroll
      for (int ni = 0; ni < 4; ni++) {
        int col = bn * 128 + wn + ni * 16 + l16;
        int which = col / 768;
        int cc = col - which * 768;
        int h = cc / 96;
        int d = cc - h * 96;
        int base = ((which * 64 + b * 8 + h) * 1024 + t) * 96 + d;
#pragma unroll
        for (int r = 0; r < 4; r++) obf[base + r * 96] = f2bf(acc[mi][ni][r]);
      }
    } else {
#pragma unroll
      for (int ni = 0; ni < 4; ni++) {
        int col = bn * 128 + wn + ni * 16 + l16;
#pragma unroll
        for (int r = 0; r < 4; r++) of32[(row + r) * 768 + col] = acc[mi][ni][r];
      }
    }
  }
}

// ---- flash attention v5: S^T formulation, P in registers, m-tiles sequential ----
// Same structure as v4 but: __launch_bounds__(256,2) (v3/v4's (256,3) cap ~168 VGPR
// forced wholesale array spill -> 7 GB scratch traffic), VS=136 (8B-aligned PV reads).
__global__ __launch_bounds__(256, 2)
void attn(const unsigned short* __restrict__ qkv, unsigned short* __restrict__ y) {
  const int bh = blockIdx.x;
  const int q0 = (7 - blockIdx.y) * 128;   // heavy blocks dispatch first
  const int tid = threadIdx.x;
  const int wave = tid >> 6, lane = tid & 63;
  const int quad = lane >> 4, l16 = lane & 15;
  const int qw0 = q0 + wave * 32;
  const int b = bh >> 3, h = bh & 7;

  const unsigned short* Qh = qkv + bh * Tz * Dz;
  const unsigned short* Kh = qkv + (BHz + bh) * Tz * Dz;
  const unsigned short* Vh = qkv + (2 * BHz + bh) * Tz * Dz;

  __shared__ unsigned short Vsm[96 * VS];   // V^T [d][s]

  // Q B-frags: n=l16 -> q row, k=quad*8+j -> d
  bf16x8 aq[2][3];
#pragma unroll
  for (int mi = 0; mi < 2; mi++)
#pragma unroll
    for (int kd = 0; kd < 3; kd++)
      aq[mi][kd] = *(const bf16x8*)(Qh + (qw0 + mi * 16 + l16) * Dz + kd * 32 + quad * 8);

  f32x4 zero = {0.f, 0.f, 0.f, 0.f};
  f32x4 acc_o[2][6];   // O^T: col=l16=q, row=quad*4+r=d (per 16-d tile)
#pragma unroll
  for (int mi = 0; mi < 2; mi++)
#pragma unroll
    for (int i = 0; i < 6; i++) acc_o[mi][i] = zero;
  const float NEG = -__builtin_inff();
  float mrow[2] = {NEG, NEG}, lrow[2] = {0.f, 0.f};   // per-lane: q = l16 (+16*mi)
  const float scale = 0.10206207261596577f;  // 1/sqrt(96)

  // conflict-free V^T staging map: lane = s index -> consecutive LDS addresses
  const int sg = tid & 127;
  const int g0 = tid >> 7;
  const unsigned short* Vrow = Vh + sg * Dz;

  for (int s0 = 0; s0 <= q0; s0 += 128) {
    __syncthreads();                 // WAR: prior iter's Vsm reads done
#pragma unroll
    for (int i = 0; i < 6; i++) {
      int g = g0 + 2 * i;
      u16x8 v = *(const u16x8*)(Vrow + s0 * Dz + g * 8);
#pragma unroll
      for (int jj = 0; jj < 8; jj++) Vsm[(g * 8 + jj) * VS + sg] = v[jj];
    }
    __syncthreads();                 // Vsm ready

#pragma unroll
    for (int mi = 0; mi < 2; mi++) {
      const int nl = min(7, (qw0 + mi * 16 + 15 - s0) >> 4);
      const int t_abs = qw0 + mi * 16 + l16;

      // ---- S^T = K Q^T : lane holds S^T[s=quad*4+r][q=l16] per 16-s tile
      f32x4 sacc[8];
#pragma unroll
      for (int ni = 0; ni < 8; ni++) {
        if (ni <= nl) {
          sacc[ni] = zero;
#pragma unroll
          for (int kd = 0; kd < 3; kd++) {
            bf16x8 ak = *(const bf16x8*)(Kh + (s0 + ni * 16 + l16) * Dz + kd * 32 + quad * 8);
            sacc[ni] = __builtin_amdgcn_mfma_f32_16x16x32_bf16(ak, aq[mi][kd], sacc[ni], 0, 0, 0);
          }
        }
      }

      // ---- mask + row max (per-lane scalar: q = l16)
      float rmax = NEG;
#pragma unroll
      for (int ni = 0; ni < 8; ni++) {
        if (ni <= nl) {
#pragma unroll
          for (int r = 0; r < 4; r++) {
            int s_abs = s0 + ni * 16 + quad * 4 + r;
            float v = (s_abs > t_abs) ? NEG : sacc[ni][r] * scale;
            sacc[ni][r] = v;
            rmax = fmaxf(rmax, v);
          }
        }
      }
      rmax = fmaxf(rmax, __shfl_xor(rmax, 16));
      rmax = fmaxf(rmax, __shfl_xor(rmax, 32));
      float mnew = fmaxf(mrow[mi], rmax);
      float alpha = __expf(mrow[mi] - mnew);
      mrow[mi] = mnew;
#pragma unroll
      for (int di = 0; di < 6; di++)
#pragma unroll
        for (int r = 0; r < 4; r++) acc_o[mi][di][r] *= alpha;

      // ---- exp + pack + immediate PV (P never stored; fused per s-tile)
      float rsum = 0.f;
#pragma unroll
      for (int ni = 0; ni < 8; ni++) {
        if (ni <= nl) {
          f32x4 p;
#pragma unroll
          for (int r = 0; r < 4; r++) {
            p[r] = __expf(sacc[ni][r] - mnew);   // masked -> exp(-inf)=0
            rsum += p[r];
          }
          s16x4 pk = pack4(p);
#pragma unroll
          for (int di = 0; di < 6; di++) {
            s16x4 av = *(const s16x4*)&Vsm[(di * 16 + l16) * VS + ni * 16 + quad * 4];
            acc_o[mi][di] = __builtin_amdgcn_mfma_f32_16x16x16bf16_1k(av, pk, acc_o[mi][di], 0, 0, 0);
          }
        }
      }
      rsum += __shfl_xor(rsum, 16);
      rsum += __shfl_xor(rsum, 32);
      lrow[mi] = lrow[mi] * alpha + rsum;
    }
  }

  // epilogue: lane holds O^T[d=di*16+quad*4+r][q=l16]; 8B stores, d-contiguous
#pragma unroll
  for (int mi = 0; mi < 2; mi++) {
    float linv = 1.f / lrow[mi];
    int t = qw0 + mi * 16 + l16;
#pragma unroll
    for (int di = 0; di < 6; di++) {
      union { unsigned short s[4]; uint2 u; } o;
#pragma unroll
      for (int r = 0; r < 4; r++) o.s[r] = f2bf(acc_o[mi][di][r] * linv);
      int d = di * 16 + quad * 4;
      *(uint2*)&y[(size_t)(b * Tz + t) * Cz + h * Dz + d] = o.u;
    }
  }
}

// ---- workspace layout (bytes) ----
#define OFF_XB   0u
#define OFF_WAT  12582912u            // 8192*768*2
#define OFF_WPT  16121856u            // + 2304*768*2
#define OFF_QKV  17301504u            // + 768*768*2
#define OFF_Y    55050240u            // + 3*64*1024*96*2

extern "C" void kernel_launch(void* const* d_in, const int* in_sizes, int n_in,
                              void* d_out, int out_size, void* d_ws, size_t ws_size,
                              hipStream_t stream) {
  const float* x  = (const float*)d_in[0];
  const float* Wa = (const float*)d_in[1];
  const float* Wp = (const float*)d_in[2];
  float* out = (float*)d_out;
  uint8_t* ws = (uint8_t*)d_ws;
  unsigned short* xb  = (unsigned short*)(ws + OFF_XB);
  unsigned short* Wat = (unsigned short*)(ws + OFF_WAT);
  unsigned short* Wpt = (unsigned short*)(ws + OFF_WPT);
  unsigned short* qkv = (unsigned short*)(ws + OFF_QKV);
  unsigned short* y   = (unsigned short*)(ws + OFF_Y);

  cast_f32_bf16<<<6144, 256, 0, stream>>>(x, xb);
  transpose_cast<<<dim3(36, 12), 256, 0, stream>>>(Wa, Wat, 768, 2304);
  transpose_cast<<<dim3(12, 12), 256, 0, stream>>>(Wp, Wpt, 768, 768);
  gemm128<0><<<dim3(64, 18), 256, 0, stream>>>(xb, Wat, qkv, nullptr);
  attn<<<dim3(64, 8), 256, 0, stream>>>(qkv, y);
  gemm128<1><<<dim3(64, 6), 256, 0, stream>>>(y, Wpt, nullptr, out);
}

// Round 6
// 295.906 us; speedup vs baseline: 9.5523x; 3.1000x over previous
//
#include <hip/hip_runtime.h>
#include <stdint.h>

// ---- problem constants ----
#define Bz 8
#define Tz 1024
#define Cz 768
#define Hz 8
#define Dz 96
#define BHz 64            // Bz*Hz
#define Kz 768
#define VS 136            // Vsm stride (elems): keeps b64 PV reads 8B-aligned, ~2 lanes/bank

typedef __bf16 bf16x8 __attribute__((ext_vector_type(8)));
typedef unsigned short u16x8 __attribute__((ext_vector_type(8)));
typedef float f32x4 __attribute__((ext_vector_type(4)));
typedef short s16x4 __attribute__((ext_vector_type(4)));

__device__ __forceinline__ unsigned short f2bf(float f) {
  union { float f; unsigned int u; } v; v.f = f;
  unsigned int u = v.u;
  return (unsigned short)((u + 0x7fffu + ((u >> 16) & 1u)) >> 16);
}

__device__ __forceinline__ s16x4 pack4(f32x4 p) {
  s16x4 o;
  o[0] = (short)f2bf(p[0]); o[1] = (short)f2bf(p[1]);
  o[2] = (short)f2bf(p[2]); o[3] = (short)f2bf(p[3]);
  return o;
}

// async global->LDS, 16B per lane; LDS dest is wave-uniform base (+lane*16 implicit)
typedef const __attribute__((address_space(1))) void* gas_ptr;
typedef __attribute__((address_space(3))) void* las_ptr;
__device__ __forceinline__ void gl16(const void* g, void* l) {
  __builtin_amdgcn_global_load_lds((gas_ptr)g, (las_ptr)l, 16, 0, 0);
}

// ---- cast x (fp32) -> bf16, 4 elems/thread ----
__global__ __launch_bounds__(256) void cast_f32_bf16(const float* __restrict__ in,
                                                     unsigned short* __restrict__ out) {
  int i = (blockIdx.x * 256 + threadIdx.x) * 4;
  float4 v = *(const float4*)(in + i);
  union { unsigned short s[4]; uint2 u; } o;
  o.s[0] = f2bf(v.x); o.s[1] = f2bf(v.y); o.s[2] = f2bf(v.z); o.s[3] = f2bf(v.w);
  *(uint2*)(out + i) = o.u;
}

// ---- transpose + cast: in[R][Cc] fp32 -> out[Cc][R] bf16 ----
__global__ __launch_bounds__(256) void transpose_cast(const float* __restrict__ in,
                                                      unsigned short* __restrict__ out,
                                                      int R, int Cc) {
  __shared__ unsigned short t[64][72];
  int bx = blockIdx.x * 64;   // col base of in
  int by = blockIdx.y * 64;   // row base of in
  int tid = threadIdx.x;
#pragma unroll
  for (int i = 0; i < 16; i++) {
    int idx = tid + i * 256;
    int r = idx >> 6, c = idx & 63;
    t[c][r] = f2bf(in[(by + r) * Cc + bx + c]);
  }
  __syncthreads();
#pragma unroll
  for (int i = 0; i < 16; i++) {
    int idx = tid + i * 256;
    int r = idx >> 6, c = idx & 63;
    out[(bx + r) * R + by + c] = t[r][c];
  }
}

// ---- 128x128 MFMA bf16 GEMM with global_load_lds staging (m97 structure) ----
template <int MODE>
__global__ __launch_bounds__(256)
void gemm128(const unsigned short* __restrict__ A,
             const unsigned short* __restrict__ Bt,
             unsigned short* __restrict__ obf,
             float* __restrict__ of32) {
  __shared__ unsigned short Asm[128 * 32];  // unpadded: required by global_load_lds lane order
  __shared__ unsigned short Bsm[128 * 32];
  const int tid = threadIdx.x;
  const int wave = tid >> 6, lane = tid & 63;
  const int quad = lane >> 4, l16 = lane & 15;
  const int bm = blockIdx.x, bn = blockIdx.y;
  const int wm = (wave >> 1) * 64, wn = (wave & 1) * 64;

  f32x4 zero = {0.f, 0.f, 0.f, 0.f};
  f32x4 acc[4][4];
#pragma unroll
  for (int i = 0; i < 4; i++)
#pragma unroll
    for (int j = 0; j < 4; j++) acc[i][j] = zero;

  const int rr = lane >> 2, c8 = (lane & 3) * 8;
  const unsigned short* Ag0 = A + (size_t)(bm * 128 + wave * 32 + rr) * Kz + c8;
  const unsigned short* Ag1 = Ag0 + 16 * Kz;
  const unsigned short* Bg0 = Bt + (size_t)(bn * 128 + wave * 32 + rr) * Kz + c8;
  const unsigned short* Bg1 = Bg0 + 16 * Kz;
  unsigned short* lA0 = &Asm[wave * 1024];
  unsigned short* lA1 = lA0 + 512;
  unsigned short* lB0 = &Bsm[wave * 1024];
  unsigned short* lB1 = lB0 + 512;

  for (int k0 = 0; k0 < Kz; k0 += 32) {
    __syncthreads();
    gl16(Ag0 + k0, lA0);
    gl16(Ag1 + k0, lA1);
    gl16(Bg0 + k0, lB0);
    gl16(Bg1 + k0, lB1);
    __syncthreads();
    bf16x8 af[4], bfr[4];
#pragma unroll
    for (int mi = 0; mi < 4; mi++)
      af[mi] = *(const bf16x8*)&Asm[(wm + mi * 16 + l16) * 32 + quad * 8];
#pragma unroll
    for (int ni = 0; ni < 4; ni++)
      bfr[ni] = *(const bf16x8*)&Bsm[(wn + ni * 16 + l16) * 32 + quad * 8];
#pragma unroll
    for (int mi = 0; mi < 4; mi++)
#pragma unroll
      for (int ni = 0; ni < 4; ni++)
        acc[mi][ni] = __builtin_amdgcn_mfma_f32_16x16x32_bf16(af[mi], bfr[ni], acc[mi][ni], 0, 0, 0);
  }

#pragma unroll
  for (int mi = 0; mi < 4; mi++) {
    int row = bm * 128 + wm + mi * 16 + quad * 4;
    if (MODE == 0) {
      int b = row >> 10;
      int t = row & 1023;
#pragma unroll
      for (int ni = 0; ni < 4; ni++) {
        int col = bn * 128 + wn + ni * 16 + l16;
        int which = col / 768;
        int cc = col - which * 768;
        int h = cc / 96;
        int d = cc - h * 96;
        int base = ((which * 64 + b * 8 + h) * 1024 + t) * 96 + d;
#pragma unroll
        for (int r = 0; r < 4; r++) obf[base + r * 96] = f2bf(acc[mi][ni][r]);
      }
    } else {
#pragma unroll
      for (int ni = 0; ni < 4; ni++) {
        int col = bn * 128 + wn + ni * 16 + l16;
#pragma unroll
        for (int r = 0; r < 4; r++) of32[(row + r) * 768 + col] = acc[mi][ni][r];
      }
    }
  }
}

// ---- flash attention v6: S^T formulation, P in registers, m-tiles sequential ----
// NOTE on launch bounds: declaring a min-waves/EU target ((256,2) or (256,3)) makes
// the allocator partition the 256-reg budget into arch/accum halves (VGPR_Count
// collapsed to 128/84 with GB-scale scratch traffic in R3-R5). Plain (256) leaves
// the full 512-reg unified file available -> no spill (same config as gemm128).
__global__ __launch_bounds__(256)
void attn(const unsigned short* __restrict__ qkv, unsigned short* __restrict__ y) {
  const int bh = blockIdx.x;
  const int q0 = (7 - blockIdx.y) * 128;   // heavy blocks dispatch first
  const int tid = threadIdx.x;
  const int wave = tid >> 6, lane = tid & 63;
  const int quad = lane >> 4, l16 = lane & 15;
  const int qw0 = q0 + wave * 32;
  const int b = bh >> 3, h = bh & 7;

  const unsigned short* Qh = qkv + bh * Tz * Dz;
  const unsigned short* Kh = qkv + (BHz + bh) * Tz * Dz;
  const unsigned short* Vh = qkv + (2 * BHz + bh) * Tz * Dz;

  __shared__ unsigned short Vsm[96 * VS];   // V^T [d][s]

  // Q B-frags: n=l16 -> q row, k=quad*8+j -> d
  bf16x8 aq[2][3];
#pragma unroll
  for (int mi = 0; mi < 2; mi++)
#pragma unroll
    for (int kd = 0; kd < 3; kd++)
      aq[mi][kd] = *(const bf16x8*)(Qh + (qw0 + mi * 16 + l16) * Dz + kd * 32 + quad * 8);

  f32x4 zero = {0.f, 0.f, 0.f, 0.f};
  f32x4 acc_o[2][6];   // O^T: col=l16=q, row=quad*4+r=d (per 16-d tile)
#pragma unroll
  for (int mi = 0; mi < 2; mi++)
#pragma unroll
    for (int i = 0; i < 6; i++) acc_o[mi][i] = zero;
  const float NEG = -__builtin_inff();
  float mrow[2] = {NEG, NEG}, lrow[2] = {0.f, 0.f};   // per-lane: q = l16 (+16*mi)
  const float scale = 0.10206207261596577f;  // 1/sqrt(96)

  // conflict-free V^T staging map: lane = s index -> consecutive LDS addresses
  const int sg = tid & 127;
  const int g0 = tid >> 7;
  const unsigned short* Vrow = Vh + sg * Dz;

  for (int s0 = 0; s0 <= q0; s0 += 128) {
    __syncthreads();                 // WAR: prior iter's Vsm reads done
#pragma unroll
    for (int i = 0; i < 6; i++) {
      int g = g0 + 2 * i;
      u16x8 v = *(const u16x8*)(Vrow + s0 * Dz + g * 8);
#pragma unroll
      for (int jj = 0; jj < 8; jj++) Vsm[(g * 8 + jj) * VS + sg] = v[jj];
    }
    __syncthreads();                 // Vsm ready

#pragma unroll
    for (int mi = 0; mi < 2; mi++) {
      const int nl = min(7, (qw0 + mi * 16 + 15 - s0) >> 4);
      const int t_abs = qw0 + mi * 16 + l16;

      // ---- S^T = K Q^T : lane holds S^T[s=quad*4+r][q=l16] per 16-s tile
      f32x4 sacc[8];
#pragma unroll
      for (int ni = 0; ni < 8; ni++) {
        if (ni <= nl) {
          sacc[ni] = zero;
#pragma unroll
          for (int kd = 0; kd < 3; kd++) {
            bf16x8 ak = *(const bf16x8*)(Kh + (s0 + ni * 16 + l16) * Dz + kd * 32 + quad * 8);
            sacc[ni] = __builtin_amdgcn_mfma_f32_16x16x32_bf16(ak, aq[mi][kd], sacc[ni], 0, 0, 0);
          }
        }
      }

      // ---- mask + row max (per-lane scalar: q = l16)
      float rmax = NEG;
#pragma unroll
      for (int ni = 0; ni < 8; ni++) {
        if (ni <= nl) {
#pragma unroll
          for (int r = 0; r < 4; r++) {
            int s_abs = s0 + ni * 16 + quad * 4 + r;
            float v = (s_abs > t_abs) ? NEG : sacc[ni][r] * scale;
            sacc[ni][r] = v;
            rmax = fmaxf(rmax, v);
          }
        }
      }
      rmax = fmaxf(rmax, __shfl_xor(rmax, 16));
      rmax = fmaxf(rmax, __shfl_xor(rmax, 32));
      float mnew = fmaxf(mrow[mi], rmax);
      float alpha = __expf(mrow[mi] - mnew);
      mrow[mi] = mnew;
#pragma unroll
      for (int di = 0; di < 6; di++)
#pragma unroll
        for (int r = 0; r < 4; r++) acc_o[mi][di][r] *= alpha;

      // ---- exp + pack + immediate PV (P never stored; fused per s-tile)
      float rsum = 0.f;
#pragma unroll
      for (int ni = 0; ni < 8; ni++) {
        if (ni <= nl) {
          f32x4 p;
#pragma unroll
          for (int r = 0; r < 4; r++) {
            p[r] = __expf(sacc[ni][r] - mnew);   // masked -> exp(-inf)=0
            rsum += p[r];
          }
          s16x4 pk = pack4(p);
#pragma unroll
          for (int di = 0; di < 6; di++) {
            s16x4 av = *(const s16x4*)&Vsm[(di * 16 + l16) * VS + ni * 16 + quad * 4];
            acc_o[mi][di] = __builtin_amdgcn_mfma_f32_16x16x16bf16_1k(av, pk, acc_o[mi][di], 0, 0, 0);
          }
        }
      }
      rsum += __shfl_xor(rsum, 16);
      rsum += __shfl_xor(rsum, 32);
      lrow[mi] = lrow[mi] * alpha + rsum;
    }
  }

  // epilogue: lane holds O^T[d=di*16+quad*4+r][q=l16]; 8B stores, d-contiguous
#pragma unroll
  for (int mi = 0; mi < 2; mi++) {
    float linv = 1.f / lrow[mi];
    int t = qw0 + mi * 16 + l16;
#pragma unroll
    for (int di = 0; di < 6; di++) {
      union { unsigned short s[4]; uint2 u; } o;
#pragma unroll
      for (int r = 0; r < 4; r++) o.s[r] = f2bf(acc_o[mi][di][r] * linv);
      int d = di * 16 + quad * 4;
      *(uint2*)&y[(size_t)(b * Tz + t) * Cz + h * Dz + d] = o.u;
    }
  }
}

// ---- workspace layout (bytes) ----
#define OFF_XB   0u
#define OFF_WAT  12582912u            // 8192*768*2
#define OFF_WPT  16121856u            // + 2304*768*2
#define OFF_QKV  17301504u            // + 768*768*2
#define OFF_Y    55050240u            // + 3*64*1024*96*2

extern "C" void kernel_launch(void* const* d_in, const int* in_sizes, int n_in,
                              void* d_out, int out_size, void* d_ws, size_t ws_size,
                              hipStream_t stream) {
  const float* x  = (const float*)d_in[0];
  const float* Wa = (const float*)d_in[1];
  const float* Wp = (const float*)d_in[2];
  float* out = (float*)d_out;
  uint8_t* ws = (uint8_t*)d_ws;
  unsigned short* xb  = (unsigned short*)(ws + OFF_XB);
  unsigned short* Wat = (unsigned short*)(ws + OFF_WAT);
  unsigned short* Wpt = (unsigned short*)(ws + OFF_WPT);
  unsigned short* qkv = (unsigned short*)(ws + OFF_QKV);
  unsigned short* y   = (unsigned short*)(ws + OFF_Y);

  cast_f32_bf16<<<6144, 256, 0, stream>>>(x, xb);
  transpose_cast<<<dim3(36, 12), 256, 0, stream>>>(Wa, Wat, 768, 2304);
  transpose_cast<<<dim3(12, 12), 256, 0, stream>>>(Wp, Wpt, 768, 768);
  gemm128<0><<<dim3(64, 18), 256, 0, stream>>>(xb, Wat, qkv, nullptr);
  attn<<<dim3(64, 8), 256, 0, stream>>>(qkv, y);
  gemm128<1><<<dim3(64, 6), 256, 0, stream>>>(y, Wpt, nullptr, out);
}